// Round 17
// baseline (142.770 us; speedup 1.0000x reference)
//
#include <hip/hip_runtime.h>
#include <hip/hip_bf16.h>
#include <stdint.h>

// GatheringLoss: score = q[32768x512] @ items[4096x512]^T, idx = argmax_row,
// out = mean((q - items[idx])^2).
// R17: vs green R16 — hoist the argmax fold out of the K-loop. Loop nest:
// for g(8){ for kc(32, unroll4){ loads+MFMA only } fold(g) }. Hot body
// shrinks ~12KB -> ~1.8KB (6 resident fold copies + 6 runtime (J&31)==31
// checks deleted); fold VALU overlaps next-group load latency. B rotation
// period 4 (bfs0..3, depth-2), A period 2 (afs0/1, depth-1) -> unroll 4.
// All layouts / fold content / argmax reduce / MSE byte-identical to R16.
// ws: [0,2MB) pk fp8 packed items | [+4MB) ihl fp16 items | [+1KB) partials

#define D_DIM 512
#define M_ITEMS 4096
#define N_ROWS 32768
#define BM 128
#define GCOLS 512            // cols per group
#define NG (M_ITEMS / GCOLS) // 8 groups
#define TOT 256              // total K=16 iterations (NG * 32)

typedef _Float16 half8 __attribute__((ext_vector_type(8)));
typedef _Float16 half4h __attribute__((ext_vector_type(4)));
typedef float f32x16 __attribute__((ext_vector_type(16)));
typedef float f32x4v __attribute__((ext_vector_type(4)));

__device__ inline unsigned pack4_fp8(float a, float b, float c, float d) {
  int v = 0;
  v = __builtin_amdgcn_cvt_pk_fp8_f32(a, b, v, false); // bytes 0,1
  v = __builtin_amdgcn_cvt_pk_fp8_f32(c, d, v, true);  // bytes 2,3
  return (unsigned)v;
}

__global__ __launch_bounds__(256) void cast_f32_f16(
    const float* __restrict__ in, _Float16* __restrict__ out, int n4) {
  const int stride = gridDim.x * blockDim.x;
  for (int i = blockIdx.x * blockDim.x + threadIdx.x; i < n4; i += stride) {
    const f32x4v v = reinterpret_cast<const f32x4v*>(in)[i];
    half4h h;
    h.x = (_Float16)v.x;
    h.y = (_Float16)v.y;
    h.z = (_Float16)v.z;
    h.w = (_Float16)v.w;
    reinterpret_cast<half4h*>(out)[i] = h;
  }
}

// pk[kc][m][16] fp8 bytes: unit u = kc*4096 + m holds items[m][kc*16..+16).
__global__ __launch_bounds__(256) void pack_items_fp8(
    const float* __restrict__ itf, unsigned char* __restrict__ pk) {
  const int u = blockIdx.x * blockDim.x + threadIdx.x; // 0..131071
  const int kc = u >> 12;
  const int m = u & 4095;
  const float* src = itf + (size_t)m * D_DIM + kc * 16;
  const f32x4v a = *reinterpret_cast<const f32x4v*>(src);
  const f32x4v b = *reinterpret_cast<const f32x4v*>(src + 4);
  const f32x4v c = *reinterpret_cast<const f32x4v*>(src + 8);
  const f32x4v d = *reinterpret_cast<const f32x4v*>(src + 12);
  uint4 o;
  o.x = pack4_fp8(a.x, a.y, a.z, a.w);
  o.y = pack4_fp8(b.x, b.y, b.z, b.w);
  o.z = pack4_fp8(c.x, c.y, c.z, c.w);
  o.w = pack4_fp8(d.x, d.y, d.z, d.w);
  *reinterpret_cast<uint4*>(pk + (size_t)u * 16) = o;
}

__global__ __launch_bounds__(512, 2) void score_mse(
    const float* __restrict__ qf, const unsigned char* __restrict__ pk,
    const _Float16* __restrict__ ihl, float* __restrict__ partials) {
  __shared__ __align__(16) unsigned char Alds8[BM * D_DIM]; // 64 KiB fp8 A
  __shared__ float sV[4][BM];
  __shared__ int sI[4][BM];
  __shared__ float sSum[8];

  const int t = threadIdx.x; // 0..511
  const int lane = t & 63;
  const int wid = t >> 6;  // 0..7
  const int wm = wid >> 2; // 0..1 (row half: 64 rows)
  const int wn = wid & 3;  // 0..3 (col quarter of 512: 128 cols)
  const int l31 = lane & 31;
  const int hsel = lane >> 5; // 0..1
  const int l7 = lane & 7;

  // T1: XCD chunking (grid 256 = 8 XCD x 32)
  const int bid = blockIdx.x;
  const int rb = (bid & 7) * 32 + (bid >> 3);
  const int row0 = rb * BM;

  // --- prologue: cast this block's 128 q rows f32->fp8 into Alds8, swizzled:
  // LDS 8B-unit (r,u) holds global k-unit u^(r&7) (8 elems).
#pragma unroll
  for (int i = 0; i < 16; ++i) {
    const int f = i * 512 + t; // 8192 units of 8B
    const int r = f >> 6;
    const int s = f & 63;
    const float* src = qf + (size_t)(row0 + r) * D_DIM + ((s ^ (r & 7)) * 8);
    const f32x4v a = *(const f32x4v*)(src);
    const f32x4v b = *(const f32x4v*)(src + 4);
    uint2 o;
    o.x = pack4_fp8(a.x, a.y, a.z, a.w);
    o.y = pack4_fp8(b.x, b.y, b.z, b.w);
    *reinterpret_cast<uint2*>(Alds8 + (size_t)f * 8) = o;
  }
  __syncthreads();

  f32x16 acc[2][4];
#pragma unroll
  for (int fr = 0; fr < 2; ++fr)
#pragma unroll
    for (int fc = 0; fc < 4; ++fc) acc[fr][fc] = (f32x16)(0.0f);
  float rmax[2][16];
  unsigned rid16[16]; // packed idx: bits [15:0]=fr0, [31:16]=fr1
#pragma unroll
  for (int rg = 0; rg < 16; ++rg) {
    rmax[0][rg] = -3.0e38f;
    rmax[1][rg] = -3.0e38f;
    rid16[rg] = 0u;
  }

  // A-frag row byte-offsets (row*512B); row&7 == l7 for both rows.
  const int arow0 = (wm * 64 + l31) * D_DIM;
  const int arow1 = (wm * 64 + 32 + l31) * D_DIM;
  // B per-thread base: 16B units, lane reads 8B half by hsel.
  const unsigned char* bbase = pk + ((size_t)(wn * 128 + l31) << 4) + hsel * 8;

#define LOADB(J, BF)                                                           \
  do {                                                                         \
    const int g_ = (J) >> 5, kc_ = (J) & 31;                                   \
    const unsigned char* p_ = bbase + (((size_t)kc_ * 4096 + g_ * 512) << 4);  \
    BF[0] = *(const unsigned long*)(p_);                                       \
    BF[1] = *(const unsigned long*)(p_ + (32 << 4));                           \
    BF[2] = *(const unsigned long*)(p_ + (64 << 4));                           \
    BF[3] = *(const unsigned long*)(p_ + (96 << 4));                           \
  } while (0)

#define LOADA(J, A0, A1)                                                       \
  do {                                                                         \
    const int kca_ = (J) & 31;                                                 \
    const int aslot_ = ((kca_ * 2 + hsel) ^ l7) * 8;                           \
    A0 = *(const unsigned long*)(Alds8 + arow0 + aslot_);                      \
    A1 = *(const unsigned long*)(Alds8 + arow1 + aslot_);                      \
  } while (0)

// lite body: prefetch B(n+2) and A(n+1), then 8 MFMAs. No fold, no checks
// beyond the uniform tail guards.
#define BODY(n, BC, BN, A0c, A1c, A0n, A1n)                                    \
  do {                                                                         \
    if ((n) + 2 < TOT) LOADB((n) + 2, BN);                                     \
    if ((n) + 1 < TOT) LOADA((n) + 1, A0n, A1n);                               \
    _Pragma("unroll") for (int fc = 0; fc < 4; ++fc) {                         \
      acc[0][fc] = __builtin_amdgcn_mfma_f32_32x32x16_fp8_fp8(                 \
          (long)A0c, (long)BC[fc], acc[0][fc], 0, 0, 0);                       \
      acc[1][fc] = __builtin_amdgcn_mfma_f32_32x32x16_fp8_fp8(                 \
          (long)A1c, (long)BC[fc], acc[1][fc], 0, 0, 0);                       \
    }                                                                          \
  } while (0)

  unsigned long bfs0[4], bfs1[4], bfs2[4], bfs3[4];
  unsigned long afs0a, afs0b, afs1a, afs1b;
  LOADB(0, bfs0);
  LOADB(1, bfs1);
  LOADA(0, afs0a, afs0b);

#pragma unroll 1
  for (int g = 0; g < NG; ++g) {
#pragma unroll 1
    for (int kc = 0; kc < 32; kc += 4) {
      const int n = g * 32 + kc;
      // n%4 = kc%4 (32%4==0); n%2 = kc%2.
      BODY(n + 0, bfs0, bfs2, afs0a, afs0b, afs1a, afs1b);
      BODY(n + 1, bfs1, bfs3, afs1a, afs1b, afs0a, afs0b);
      BODY(n + 2, bfs2, bfs0, afs0a, afs0b, afs1a, afs1b);
      BODY(n + 3, bfs3, bfs1, afs1a, afs1b, afs0a, afs0b);
    }
    // --- group fold (hoisted): cols ascend with fc and with g ->
    // strict > keeps lowest index. Overlaps next-group load latency.
    {
      const int colbase = g * GCOLS + wn * 128 + l31;
#pragma unroll
      for (int fr = 0; fr < 2; ++fr)
#pragma unroll
        for (int rg = 0; rg < 16; ++rg) {
          float v = acc[fr][0][rg];
          int c = colbase;
#pragma unroll
          for (int fc = 1; fc < 4; ++fc) {
            const float vv = acc[fr][fc][rg];
            if (vv > v) {
              v = vv;
              c = colbase + fc * 32;
            }
          }
          if (v > rmax[fr][rg]) {
            rmax[fr][rg] = v;
            rid16[rg] = (rid16[rg] & (fr ? 0x0000FFFFu : 0xFFFF0000u)) |
                        ((unsigned)c << (fr * 16));
          }
        }
#pragma unroll
      for (int fr = 0; fr < 2; ++fr)
#pragma unroll
        for (int fc = 0; fc < 4; ++fc) acc[fr][fc] = (f32x16)(0.0f);
    }
  }

  // --- argmax block reduce. C/D layout (m74/m101): col = lane&31,
  // row = (rg&3) + 8*(rg>>2) + 4*(lane>>5).
  float bv = -3.0e38f;
  int bi = 0;
#pragma unroll
  for (int fr = 0; fr < 2; ++fr)
#pragma unroll
    for (int rg = 0; rg < 16; ++rg) {
      float v = rmax[fr][rg];
      int c = (int)((rid16[rg] >> (fr * 16)) & 0xFFFFu);
#pragma unroll
      for (int m = 1; m < 32; m <<= 1) {
        const float ov = __shfl_xor(v, m, 64);
        const int oc = __shfl_xor(c, m, 64);
        if (ov > v || (ov == v && oc < c)) {
          v = ov;
          c = oc;
        }
      }
      if (l31 == fr * 16 + rg) {
        bv = v;
        bi = c;
      }
    }
  const int e = l31;
  const int row_local =
      wm * 64 + (e >> 4) * 32 + ((e & 3) + 8 * ((e >> 2) & 3)) + 4 * hsel;

  sV[wn][row_local] = bv;
  sI[wn][row_local] = bi;
  __syncthreads();
  if (t < BM) {
    float fv = sV[0][t];
    int fi = sI[0][t];
#pragma unroll
    for (int w = 1; w < 4; ++w) {
      const float v = sV[w][t];
      const int ii = sI[w][t];
      if (v > fv || (v == fv && ii < fi)) {
        fv = v;
        fi = ii;
      }
    }
    sI[0][t] = fi; // merged winner per row
  }
  __syncthreads();

  // --- fused MSE epilogue: wave wid handles rows wid*16..+15.
  // q EXACT from global f32; gathered item from fp16 ihl.
  float lsum = 0.0f;
#pragma unroll 1
  for (int rr = 0; rr < 16; ++rr) {
    const int r = wid * 16 + rr;
    const int fi = sI[0][r];
    const float* qr = qf + (size_t)(row0 + r) * D_DIM + lane * 8;
    const f32x4v a0 = *(const f32x4v*)(qr);
    const f32x4v a1 = *(const f32x4v*)(qr + 4);
    const half8 ag = *(const half8*)(ihl + (size_t)fi * D_DIM + lane * 8);
    const float d0 = a0.x - (float)ag[0], d1 = a0.y - (float)ag[1];
    const float d2 = a0.z - (float)ag[2], d3 = a0.w - (float)ag[3];
    const float d4 = a1.x - (float)ag[4], d5 = a1.y - (float)ag[5];
    const float d6 = a1.z - (float)ag[6], d7 = a1.w - (float)ag[7];
    lsum += d0 * d0 + d1 * d1 + d2 * d2 + d3 * d3 + d4 * d4 + d5 * d5 +
            d6 * d6 + d7 * d7;
  }
#pragma unroll
  for (int m = 1; m < 64; m <<= 1) lsum += __shfl_xor(lsum, m, 64);
  if (lane == 0) sSum[wid] = lsum;
  __syncthreads();
  if (t == 0) {
    float s = 0.0f;
#pragma unroll
    for (int w = 0; w < 8; ++w) s += sSum[w];
    partials[bid] = s;
  }
}

__global__ __launch_bounds__(256) void final_reduce(
    const float* __restrict__ partials, float* __restrict__ out) {
  __shared__ float sS[4];
  const int t = threadIdx.x;
  float v = partials[t]; // exactly 256 partials
#pragma unroll
  for (int m = 1; m < 64; m <<= 1) v += __shfl_xor(v, m, 64);
  if ((t & 63) == 0) sS[t >> 6] = v;
  __syncthreads();
  if (t == 0)
    out[0] = (sS[0] + sS[1] + sS[2] + sS[3]) *
             (1.0f / ((float)N_ROWS * (float)D_DIM));
}

extern "C" void kernel_launch(void* const* d_in, const int* in_sizes, int n_in,
                              void* d_out, int out_size, void* d_ws,
                              size_t ws_size, hipStream_t stream) {
  const float* qf = (const float*)d_in[0];  // [32768][512]
  const float* itf = (const float*)d_in[1]; // [4096][512]
  char* ws = (char*)d_ws;
  unsigned char* pk = (unsigned char*)ws;                        // 2 MB fp8
  _Float16* ihl = (_Float16*)(ws + (size_t)M_ITEMS * D_DIM);     // 4 MB fp16
  float* partials =
      (float*)(ws + (size_t)M_ITEMS * D_DIM + (size_t)M_ITEMS * D_DIM * 2);
  float* out = (float*)d_out;

  cast_f32_f16<<<512, 256, 0, stream>>>(itf, ihl, M_ITEMS * D_DIM / 4);
  pack_items_fp8<<<512, 256, 0, stream>>>(itf, pk);
  score_mse<<<N_ROWS / BM, 512, 0, stream>>>(qf, pk, ihl, partials);
  final_reduce<<<1, 256, 0, stream>>>(partials, out);
}

// Round 18
// 135.946 us; speedup vs baseline: 1.0502x; 1.0502x over previous
//
#include <hip/hip_runtime.h>
#include <hip/hip_bf16.h>
#include <stdint.h>

// GatheringLoss: score = q[32768x512] @ items[4096x512]^T, idx = argmax_row,
// out = mean((q - items[idx])^2).
// R18: REVERT to R16 (green best, 136.0us). R17's fold-hoist regressed
// (135->153us): the in-loop fold was co-scheduling under MFMA bursts for
// free; hoisting created an unoverlapped VALU burst per group + VGPR 108->116.
// R16 = fp8-e4m3 scoring, 2M x 4N waves, barrier-free loop, B depth-2
// (3-set rotation), A register double-buffer (period 2), float argmax with
// fr-packed rid16, fused q-cast prologue (f32->fp8 LDS) + exact MSE epilogue
// (q f32, items fp16).
// ws: [0,2MB) pk fp8 packed items | [+4MB) ihl fp16 items | [+1KB) partials

#define D_DIM 512
#define M_ITEMS 4096
#define N_ROWS 32768
#define BM 128
#define GCOLS 512            // cols per group
#define NG (M_ITEMS / GCOLS) // 8 groups
#define NKC (D_DIM / 16)     // 32 k-chunks per group
#define TOT (NG * NKC)       // 256 iterations

typedef _Float16 half8 __attribute__((ext_vector_type(8)));
typedef _Float16 half4h __attribute__((ext_vector_type(4)));
typedef float f32x16 __attribute__((ext_vector_type(16)));
typedef float f32x4v __attribute__((ext_vector_type(4)));

__device__ inline unsigned pack4_fp8(float a, float b, float c, float d) {
  int v = 0;
  v = __builtin_amdgcn_cvt_pk_fp8_f32(a, b, v, false); // bytes 0,1
  v = __builtin_amdgcn_cvt_pk_fp8_f32(c, d, v, true);  // bytes 2,3
  return (unsigned)v;
}

__global__ __launch_bounds__(256) void cast_f32_f16(
    const float* __restrict__ in, _Float16* __restrict__ out, int n4) {
  const int stride = gridDim.x * blockDim.x;
  for (int i = blockIdx.x * blockDim.x + threadIdx.x; i < n4; i += stride) {
    const f32x4v v = reinterpret_cast<const f32x4v*>(in)[i];
    half4h h;
    h.x = (_Float16)v.x;
    h.y = (_Float16)v.y;
    h.z = (_Float16)v.z;
    h.w = (_Float16)v.w;
    reinterpret_cast<half4h*>(out)[i] = h;
  }
}

// pk[kc][m][16] fp8 bytes: unit u = kc*4096 + m holds items[m][kc*16..+16).
__global__ __launch_bounds__(256) void pack_items_fp8(
    const float* __restrict__ itf, unsigned char* __restrict__ pk) {
  const int u = blockIdx.x * blockDim.x + threadIdx.x; // 0..131071
  const int kc = u >> 12;
  const int m = u & 4095;
  const float* src = itf + (size_t)m * D_DIM + kc * 16;
  const f32x4v a = *reinterpret_cast<const f32x4v*>(src);
  const f32x4v b = *reinterpret_cast<const f32x4v*>(src + 4);
  const f32x4v c = *reinterpret_cast<const f32x4v*>(src + 8);
  const f32x4v d = *reinterpret_cast<const f32x4v*>(src + 12);
  uint4 o;
  o.x = pack4_fp8(a.x, a.y, a.z, a.w);
  o.y = pack4_fp8(b.x, b.y, b.z, b.w);
  o.z = pack4_fp8(c.x, c.y, c.z, c.w);
  o.w = pack4_fp8(d.x, d.y, d.z, d.w);
  *reinterpret_cast<uint4*>(pk + (size_t)u * 16) = o;
}

__global__ __launch_bounds__(512, 2) void score_mse(
    const float* __restrict__ qf, const unsigned char* __restrict__ pk,
    const _Float16* __restrict__ ihl, float* __restrict__ partials) {
  __shared__ __align__(16) unsigned char Alds8[BM * D_DIM]; // 64 KiB fp8 A
  __shared__ float sV[4][BM];
  __shared__ int sI[4][BM];
  __shared__ float sSum[8];

  const int t = threadIdx.x; // 0..511
  const int lane = t & 63;
  const int wid = t >> 6;  // 0..7
  const int wm = wid >> 2; // 0..1 (row half: 64 rows)
  const int wn = wid & 3;  // 0..3 (col quarter of 512: 128 cols)
  const int l31 = lane & 31;
  const int hsel = lane >> 5; // 0..1
  const int l7 = lane & 7;

  // T1: XCD chunking (grid 256 = 8 XCD x 32)
  const int bid = blockIdx.x;
  const int rb = (bid & 7) * 32 + (bid >> 3);
  const int row0 = rb * BM;

  // --- prologue: cast this block's 128 q rows f32->fp8 into Alds8, swizzled:
  // LDS 8B-unit (r,u) holds global k-unit u^(r&7) (8 elems).
#pragma unroll
  for (int i = 0; i < 16; ++i) {
    const int f = i * 512 + t; // 8192 units of 8B
    const int r = f >> 6;
    const int s = f & 63;
    const float* src = qf + (size_t)(row0 + r) * D_DIM + ((s ^ (r & 7)) * 8);
    const f32x4v a = *(const f32x4v*)(src);
    const f32x4v b = *(const f32x4v*)(src + 4);
    uint2 o;
    o.x = pack4_fp8(a.x, a.y, a.z, a.w);
    o.y = pack4_fp8(b.x, b.y, b.z, b.w);
    *reinterpret_cast<uint2*>(Alds8 + (size_t)f * 8) = o;
  }
  __syncthreads();

  f32x16 acc[2][4];
#pragma unroll
  for (int fr = 0; fr < 2; ++fr)
#pragma unroll
    for (int fc = 0; fc < 4; ++fc) acc[fr][fc] = (f32x16)(0.0f);
  float rmax[2][16];
  unsigned rid16[16]; // packed idx: bits [15:0]=fr0, [31:16]=fr1
#pragma unroll
  for (int rg = 0; rg < 16; ++rg) {
    rmax[0][rg] = -3.0e38f;
    rmax[1][rg] = -3.0e38f;
    rid16[rg] = 0u;
  }

  // A-frag row byte-offsets (row*512B); row&7 == l7 for both rows.
  const int arow0 = (wm * 64 + l31) * D_DIM;
  const int arow1 = (wm * 64 + 32 + l31) * D_DIM;
  // B per-thread base: 16B units, lane reads 8B half by hsel.
  const unsigned char* bbase = pk + ((size_t)(wn * 128 + l31) << 4) + hsel * 8;

#define LOADB(J, BF)                                                           \
  do {                                                                         \
    const int g_ = (J) >> 5, kc_ = (J) & 31;                                   \
    const unsigned char* p_ = bbase + (((size_t)kc_ * 4096 + g_ * 512) << 4);  \
    BF[0] = *(const unsigned long*)(p_);                                       \
    BF[1] = *(const unsigned long*)(p_ + (32 << 4));                           \
    BF[2] = *(const unsigned long*)(p_ + (64 << 4));                           \
    BF[3] = *(const unsigned long*)(p_ + (96 << 4));                           \
  } while (0)

#define LOADA(J, A0, A1)                                                       \
  do {                                                                         \
    const int kca_ = (J) & 31;                                                 \
    const int aslot_ = ((kca_ * 2 + hsel) ^ l7) * 8;                           \
    A0 = *(const unsigned long*)(Alds8 + arow0 + aslot_);                      \
    A1 = *(const unsigned long*)(Alds8 + arow1 + aslot_);                      \
  } while (0)

// compute J with (A0c,A1c,BC); prefetch A(J+1) into (A0n,A1n) and B(J+2)
// into BN before the MFMA burst so both latencies hide under it.
#define BODY(J, BC, BN, A0c, A1c, A0n, A1n)                                    \
  do {                                                                         \
    if ((J) + 2 < TOT) LOADB((J) + 2, BN);                                     \
    if ((J) + 1 < TOT) LOADA((J) + 1, A0n, A1n);                               \
    _Pragma("unroll") for (int fc = 0; fc < 4; ++fc) {                         \
      acc[0][fc] = __builtin_amdgcn_mfma_f32_32x32x16_fp8_fp8(                 \
          (long)A0c, (long)BC[fc], acc[0][fc], 0, 0, 0);                       \
      acc[1][fc] = __builtin_amdgcn_mfma_f32_32x32x16_fp8_fp8(                 \
          (long)A1c, (long)BC[fc], acc[1][fc], 0, 0, 0);                       \
    }                                                                          \
    if (((J) & 31) == 31) {                                                    \
      const int colbase_ = ((J) >> 5) * GCOLS + wn * 128 + l31;                \
      _Pragma("unroll") for (int fr = 0; fr < 2; ++fr)                         \
          _Pragma("unroll") for (int rg = 0; rg < 16; ++rg) {                  \
        float v_ = acc[fr][0][rg];                                             \
        int c_ = colbase_;                                                     \
        _Pragma("unroll") for (int fc = 1; fc < 4; ++fc) {                     \
          const float vv_ = acc[fr][fc][rg];                                   \
          if (vv_ > v_) {                                                      \
            v_ = vv_;                                                          \
            c_ = colbase_ + fc * 32;                                           \
          }                                                                    \
        }                                                                      \
        if (v_ > rmax[fr][rg]) {                                               \
          rmax[fr][rg] = v_;                                                   \
          rid16[rg] = (rid16[rg] & (fr ? 0x0000FFFFu : 0xFFFF0000u)) |         \
                      ((unsigned)c_ << (fr * 16));                             \
        }                                                                      \
      }                                                                        \
      _Pragma("unroll") for (int fr = 0; fr < 2; ++fr)                         \
          _Pragma("unroll") for (int fc = 0; fc < 4; ++fc) acc[fr][fc] =       \
              (f32x16)(0.0f);                                                  \
    }                                                                          \
  } while (0)

  unsigned long bf0[4], bf1[4], bf2[4];
  unsigned long afA0, afA1, afB0, afB1;
  LOADB(0, bf0);
  LOADB(1, bf1);
  LOADA(0, afA0, afA1);
#pragma unroll 1
  for (int J = 0; J < 252; J += 6) { // 42 x 6 bodies = J 0..251
    BODY(J + 0, bf0, bf2, afA0, afA1, afB0, afB1);
    BODY(J + 1, bf1, bf0, afB0, afB1, afA0, afA1);
    BODY(J + 2, bf2, bf1, afA0, afA1, afB0, afB1);
    BODY(J + 3, bf0, bf2, afB0, afB1, afA0, afA1);
    BODY(J + 4, bf1, bf0, afA0, afA1, afB0, afB1);
    BODY(J + 5, bf2, bf1, afB0, afB1, afA0, afA1);
  }
  // tail J = 252..255 (rotations continue: 252%3=0, 252%2=0)
  BODY(252, bf0, bf2, afA0, afA1, afB0, afB1);
  BODY(253, bf1, bf0, afB0, afB1, afA0, afA1);
  BODY(254, bf2, bf1, afA0, afA1, afB0, afB1);
  BODY(255, bf0, bf1, afB0, afB1, afA0, afA1); // prefetches guarded off

  // --- argmax block reduce. C/D layout (m74/m101): col = lane&31,
  // row = (rg&3) + 8*(rg>>2) + 4*(lane>>5).
  float bv = -3.0e38f;
  int bi = 0;
#pragma unroll
  for (int fr = 0; fr < 2; ++fr)
#pragma unroll
    for (int rg = 0; rg < 16; ++rg) {
      float v = rmax[fr][rg];
      int c = (int)((rid16[rg] >> (fr * 16)) & 0xFFFFu);
#pragma unroll
      for (int m = 1; m < 32; m <<= 1) {
        const float ov = __shfl_xor(v, m, 64);
        const int oc = __shfl_xor(c, m, 64);
        if (ov > v || (ov == v && oc < c)) {
          v = ov;
          c = oc;
        }
      }
      if (l31 == fr * 16 + rg) {
        bv = v;
        bi = c;
      }
    }
  const int e = l31;
  const int row_local =
      wm * 64 + (e >> 4) * 32 + ((e & 3) + 8 * ((e >> 2) & 3)) + 4 * hsel;

  sV[wn][row_local] = bv;
  sI[wn][row_local] = bi;
  __syncthreads();
  if (t < BM) {
    float fv = sV[0][t];
    int fi = sI[0][t];
#pragma unroll
    for (int w = 1; w < 4; ++w) {
      const float v = sV[w][t];
      const int ii = sI[w][t];
      if (v > fv || (v == fv && ii < fi)) {
        fv = v;
        fi = ii;
      }
    }
    sI[0][t] = fi; // merged winner per row
  }
  __syncthreads();

  // --- fused MSE epilogue: wave wid handles rows wid*16..+15.
  // q EXACT from global f32; gathered item from fp16 ihl.
  float lsum = 0.0f;
#pragma unroll 1
  for (int rr = 0; rr < 16; ++rr) {
    const int r = wid * 16 + rr;
    const int fi = sI[0][r];
    const float* qr = qf + (size_t)(row0 + r) * D_DIM + lane * 8;
    const f32x4v a0 = *(const f32x4v*)(qr);
    const f32x4v a1 = *(const f32x4v*)(qr + 4);
    const half8 ag = *(const half8*)(ihl + (size_t)fi * D_DIM + lane * 8);
    const float d0 = a0.x - (float)ag[0], d1 = a0.y - (float)ag[1];
    const float d2 = a0.z - (float)ag[2], d3 = a0.w - (float)ag[3];
    const float d4 = a1.x - (float)ag[4], d5 = a1.y - (float)ag[5];
    const float d6 = a1.z - (float)ag[6], d7 = a1.w - (float)ag[7];
    lsum += d0 * d0 + d1 * d1 + d2 * d2 + d3 * d3 + d4 * d4 + d5 * d5 +
            d6 * d6 + d7 * d7;
  }
#pragma unroll
  for (int m = 1; m < 64; m <<= 1) lsum += __shfl_xor(lsum, m, 64);
  if (lane == 0) sSum[wid] = lsum;
  __syncthreads();
  if (t == 0) {
    float s = 0.0f;
#pragma unroll
    for (int w = 0; w < 8; ++w) s += sSum[w];
    partials[bid] = s;
  }
}

__global__ __launch_bounds__(256) void final_reduce(
    const float* __restrict__ partials, float* __restrict__ out) {
  __shared__ float sS[4];
  const int t = threadIdx.x;
  float v = partials[t]; // exactly 256 partials
#pragma unroll
  for (int m = 1; m < 64; m <<= 1) v += __shfl_xor(v, m, 64);
  if ((t & 63) == 0) sS[t >> 6] = v;
  __syncthreads();
  if (t == 0)
    out[0] = (sS[0] + sS[1] + sS[2] + sS[3]) *
             (1.0f / ((float)N_ROWS * (float)D_DIM));
}

extern "C" void kernel_launch(void* const* d_in, const int* in_sizes, int n_in,
                              void* d_out, int out_size, void* d_ws,
                              size_t ws_size, hipStream_t stream) {
  const float* qf = (const float*)d_in[0];  // [32768][512]
  const float* itf = (const float*)d_in[1]; // [4096][512]
  char* ws = (char*)d_ws;
  unsigned char* pk = (unsigned char*)ws;                        // 2 MB fp8
  _Float16* ihl = (_Float16*)(ws + (size_t)M_ITEMS * D_DIM);     // 4 MB fp16
  float* partials =
      (float*)(ws + (size_t)M_ITEMS * D_DIM + (size_t)M_ITEMS * D_DIM * 2);
  float* out = (float*)d_out;

  cast_f32_f16<<<512, 256, 0, stream>>>(itf, ihl, M_ITEMS * D_DIM / 4);
  pack_items_fp8<<<512, 256, 0, stream>>>(itf, pk);
  score_mse<<<N_ROWS / BM, 512, 0, stream>>>(qf, pk, ihl, partials);
  final_reduce<<<1, 256, 0, stream>>>(partials, out);
}

// Round 19
// 111.842 us; speedup vs baseline: 1.2765x; 1.2155x over previous
//
#include <hip/hip_runtime.h>
#include <hip/hip_bf16.h>
#include <stdint.h>

// GatheringLoss: score = q[32768x512] @ items[4096x512]^T, idx = argmax_row,
// out = mean((q - items[idx])^2).
// R19: MX-scaled fp8 on the green R18 skeleton. mfma_scale_f32_32x32x64_
// f8f6f4 with unit scales (E8M0 127 = x1.0) == plain fp8 math at 2x rate:
// pipe work per K-step halves (8 x 68.8cyc vs 32 x 32.3cyc). 64 iterations
// (8 groups x 8 k64-chunks). Same pk[kc16][m][16] layout (lane reads two
// coalesced 16B units 64KB apart per B frag); same Alds8 fp8 prologue +
// XOR-8 swizzle (4 x b64 per A frag); same 2M x 4N waves, float argmax,
// butterfly, sV/sI merge, exact MSE epilogue — all byte-identical to R18.
// No prefetch sets (reg budget ~250); 2 waves interleave across 64 big iters.
// ws: [0,2MB) pk fp8 packed items | [+4MB) ihl fp16 items | [+1KB) partials

#define D_DIM 512
#define M_ITEMS 4096
#define N_ROWS 32768
#define BM 128
#define GCOLS 512            // cols per group
#define NG (M_ITEMS / GCOLS) // 8 groups
#define TOT64 64             // NG * 8 K=64 chunks

typedef _Float16 half8 __attribute__((ext_vector_type(8)));
typedef _Float16 half4h __attribute__((ext_vector_type(4)));
typedef float f32x16 __attribute__((ext_vector_type(16)));
typedef float f32x4v __attribute__((ext_vector_type(4)));
typedef int i32x8 __attribute__((ext_vector_type(8)));

__device__ inline unsigned pack4_fp8(float a, float b, float c, float d) {
  int v = 0;
  v = __builtin_amdgcn_cvt_pk_fp8_f32(a, b, v, false); // bytes 0,1
  v = __builtin_amdgcn_cvt_pk_fp8_f32(c, d, v, true);  // bytes 2,3
  return (unsigned)v;
}

__global__ __launch_bounds__(256) void cast_f32_f16(
    const float* __restrict__ in, _Float16* __restrict__ out, int n4) {
  const int stride = gridDim.x * blockDim.x;
  for (int i = blockIdx.x * blockDim.x + threadIdx.x; i < n4; i += stride) {
    const f32x4v v = reinterpret_cast<const f32x4v*>(in)[i];
    half4h h;
    h.x = (_Float16)v.x;
    h.y = (_Float16)v.y;
    h.z = (_Float16)v.z;
    h.w = (_Float16)v.w;
    reinterpret_cast<half4h*>(out)[i] = h;
  }
}

// pk[kc][m][16] fp8 bytes: unit u = kc*4096 + m holds items[m][kc*16..+16).
__global__ __launch_bounds__(256) void pack_items_fp8(
    const float* __restrict__ itf, unsigned char* __restrict__ pk) {
  const int u = blockIdx.x * blockDim.x + threadIdx.x; // 0..131071
  const int kc = u >> 12;
  const int m = u & 4095;
  const float* src = itf + (size_t)m * D_DIM + kc * 16;
  const f32x4v a = *reinterpret_cast<const f32x4v*>(src);
  const f32x4v b = *reinterpret_cast<const f32x4v*>(src + 4);
  const f32x4v c = *reinterpret_cast<const f32x4v*>(src + 8);
  const f32x4v d = *reinterpret_cast<const f32x4v*>(src + 12);
  uint4 o;
  o.x = pack4_fp8(a.x, a.y, a.z, a.w);
  o.y = pack4_fp8(b.x, b.y, b.z, b.w);
  o.z = pack4_fp8(c.x, c.y, c.z, c.w);
  o.w = pack4_fp8(d.x, d.y, d.z, d.w);
  *reinterpret_cast<uint4*>(pk + (size_t)u * 16) = o;
}

__global__ __launch_bounds__(512, 2) void score_mse(
    const float* __restrict__ qf, const unsigned char* __restrict__ pk,
    const _Float16* __restrict__ ihl, float* __restrict__ partials) {
  __shared__ __align__(16) unsigned char Alds8[BM * D_DIM]; // 64 KiB fp8 A
  __shared__ float sV[4][BM];
  __shared__ int sI[4][BM];
  __shared__ float sSum[8];

  const int t = threadIdx.x; // 0..511
  const int lane = t & 63;
  const int wid = t >> 6;  // 0..7
  const int wm = wid >> 2; // 0..1 (row half: 64 rows)
  const int wn = wid & 3;  // 0..3 (col quarter of 512: 128 cols)
  const int l31 = lane & 31;
  const int hsel = lane >> 5; // 0..1
  const int l7 = lane & 7;

  // T1: XCD chunking (grid 256 = 8 XCD x 32)
  const int bid = blockIdx.x;
  const int rb = (bid & 7) * 32 + (bid >> 3);
  const int row0 = rb * BM;

  // --- prologue: cast this block's 128 q rows f32->fp8 into Alds8, swizzled:
  // LDS 8B-unit (r,u) holds global k-unit u^(r&7) (8 elems).
#pragma unroll
  for (int i = 0; i < 16; ++i) {
    const int f = i * 512 + t; // 8192 units of 8B
    const int r = f >> 6;
    const int s = f & 63;
    const float* src = qf + (size_t)(row0 + r) * D_DIM + ((s ^ (r & 7)) * 8);
    const f32x4v a = *(const f32x4v*)(src);
    const f32x4v b = *(const f32x4v*)(src + 4);
    uint2 o;
    o.x = pack4_fp8(a.x, a.y, a.z, a.w);
    o.y = pack4_fp8(b.x, b.y, b.z, b.w);
    *reinterpret_cast<uint2*>(Alds8 + (size_t)f * 8) = o;
  }
  __syncthreads();

  f32x16 acc[2][4];
#pragma unroll
  for (int fr = 0; fr < 2; ++fr)
#pragma unroll
    for (int fc = 0; fc < 4; ++fc) acc[fr][fc] = (f32x16)(0.0f);
  float rmax[2][16];
  unsigned rid16[16]; // packed idx: bits [15:0]=fr0, [31:16]=fr1
#pragma unroll
  for (int rg = 0; rg < 16; ++rg) {
    rmax[0][rg] = -3.0e38f;
    rmax[1][rg] = -3.0e38f;
    rid16[rg] = 0u;
  }

  // A-frag row byte-offsets (row*512B); row&7 == l7 for both rows.
  const int arow0 = (wm * 64 + l31) * D_DIM;
  const int arow1 = (wm * 64 + 32 + l31) * D_DIM;

// A frag for K=64 chunk kc64 = J&7: global 8B-units u = kc64*8 + hsel*4 + j,
// j=0..3, LDS slot = u ^ l7 (row&7 == l7). k ascends across regs.
#define LOADA8(J, AROW, AV)                                                    \
  do {                                                                         \
    const int base_ = ((J) & 7) * 8 + hsel * 4;                                \
    const uint2 t0_ =                                                          \
        *(const uint2*)(Alds8 + (AROW) + (((base_ + 0) ^ l7) << 3));           \
    const uint2 t1_ =                                                          \
        *(const uint2*)(Alds8 + (AROW) + (((base_ + 1) ^ l7) << 3));           \
    const uint2 t2_ =                                                          \
        *(const uint2*)(Alds8 + (AROW) + (((base_ + 2) ^ l7) << 3));           \
    const uint2 t3_ =                                                          \
        *(const uint2*)(Alds8 + (AROW) + (((base_ + 3) ^ l7) << 3));           \
    AV = (i32x8){(int)t0_.x, (int)t0_.y, (int)t1_.x, (int)t1_.y,               \
                 (int)t2_.x, (int)t2_.y, (int)t3_.x, (int)t3_.y};              \
  } while (0)

// B frag: cols g*512 + wn*128 + FC*32 + l31; k-units kc16 = kc64*4 + hsel*2
// and +1 (two coalesced 16B loads 64KB apart). k ascends across regs.
#define LOADB8(J, FC, BV)                                                      \
  do {                                                                         \
    const int g_ = (J) >> 3, kc64_ = (J) & 7;                                  \
    const unsigned char* p_ =                                                  \
        pk + (((size_t)(kc64_ * 4 + hsel * 2) * 4096 + g_ * 512 + wn * 128 +   \
               (FC) * 32 + l31)                                                \
              << 4);                                                           \
    const uint4 b0_ = *(const uint4*)(p_);                                     \
    const uint4 b1_ = *(const uint4*)(p_ + (4096 << 4));                       \
    BV = (i32x8){(int)b0_.x, (int)b0_.y, (int)b0_.z, (int)b0_.w,               \
                 (int)b1_.x, (int)b1_.y, (int)b1_.z, (int)b1_.w};              \
  } while (0)

#pragma unroll 1
  for (int J = 0; J < TOT64; ++J) {
    i32x8 av0, av1;
    LOADA8(J, arow0, av0);
    LOADA8(J, arow1, av1);
#pragma unroll
    for (int fc = 0; fc < 4; ++fc) {
      i32x8 bv;
      LOADB8(J, fc, bv);
      // cbsz=0 (fp8 e4m3), blgp=0, scale opsel 0, scale byte 127 = x1.0
      acc[0][fc] = __builtin_amdgcn_mfma_scale_f32_32x32x64_f8f6f4(
          av0, bv, acc[0][fc], 0, 0, 0, 127, 0, 127);
      acc[1][fc] = __builtin_amdgcn_mfma_scale_f32_32x32x64_f8f6f4(
          av1, bv, acc[1][fc], 0, 0, 0, 127, 0, 127);
    }
    if ((J & 7) == 7) { // group complete: fold (trusted R16 code)
      const int colbase_ = (J >> 3) * GCOLS + wn * 128 + l31;
#pragma unroll
      for (int fr = 0; fr < 2; ++fr)
#pragma unroll
        for (int rg = 0; rg < 16; ++rg) {
          float v_ = acc[fr][0][rg];
          int c_ = colbase_;
#pragma unroll
          for (int fc = 1; fc < 4; ++fc) {
            const float vv_ = acc[fr][fc][rg];
            if (vv_ > v_) {
              v_ = vv_;
              c_ = colbase_ + fc * 32;
            }
          }
          if (v_ > rmax[fr][rg]) {
            rmax[fr][rg] = v_;
            rid16[rg] = (rid16[rg] & (fr ? 0x0000FFFFu : 0xFFFF0000u)) |
                        ((unsigned)c_ << (fr * 16));
          }
        }
#pragma unroll
      for (int fr = 0; fr < 2; ++fr)
#pragma unroll
        for (int fc = 0; fc < 4; ++fc) acc[fr][fc] = (f32x16)(0.0f);
    }
  }

  // --- argmax block reduce. C/D layout (m74/m101): col = lane&31,
  // row = (rg&3) + 8*(rg>>2) + 4*(lane>>5).
  float bv = -3.0e38f;
  int bi = 0;
#pragma unroll
  for (int fr = 0; fr < 2; ++fr)
#pragma unroll
    for (int rg = 0; rg < 16; ++rg) {
      float v = rmax[fr][rg];
      int c = (int)((rid16[rg] >> (fr * 16)) & 0xFFFFu);
#pragma unroll
      for (int m = 1; m < 32; m <<= 1) {
        const float ov = __shfl_xor(v, m, 64);
        const int oc = __shfl_xor(c, m, 64);
        if (ov > v || (ov == v && oc < c)) {
          v = ov;
          c = oc;
        }
      }
      if (l31 == fr * 16 + rg) {
        bv = v;
        bi = c;
      }
    }
  const int e = l31;
  const int row_local =
      wm * 64 + (e >> 4) * 32 + ((e & 3) + 8 * ((e >> 2) & 3)) + 4 * hsel;

  sV[wn][row_local] = bv;
  sI[wn][row_local] = bi;
  __syncthreads();
  if (t < BM) {
    float fv = sV[0][t];
    int fi = sI[0][t];
#pragma unroll
    for (int w = 1; w < 4; ++w) {
      const float v = sV[w][t];
      const int ii = sI[w][t];
      if (v > fv || (v == fv && ii < fi)) {
        fv = v;
        fi = ii;
      }
    }
    sI[0][t] = fi; // merged winner per row
  }
  __syncthreads();

  // --- fused MSE epilogue: wave wid handles rows wid*16..+15.
  // q EXACT from global f32; gathered item from fp16 ihl.
  float lsum = 0.0f;
#pragma unroll 1
  for (int rr = 0; rr < 16; ++rr) {
    const int r = wid * 16 + rr;
    const int fi = sI[0][r];
    const float* qr = qf + (size_t)(row0 + r) * D_DIM + lane * 8;
    const f32x4v a0 = *(const f32x4v*)(qr);
    const f32x4v a1 = *(const f32x4v*)(qr + 4);
    const half8 ag = *(const half8*)(ihl + (size_t)fi * D_DIM + lane * 8);
    const float d0 = a0.x - (float)ag[0], d1 = a0.y - (float)ag[1];
    const float d2 = a0.z - (float)ag[2], d3 = a0.w - (float)ag[3];
    const float d4 = a1.x - (float)ag[4], d5 = a1.y - (float)ag[5];
    const float d6 = a1.z - (float)ag[6], d7 = a1.w - (float)ag[7];
    lsum += d0 * d0 + d1 * d1 + d2 * d2 + d3 * d3 + d4 * d4 + d5 * d5 +
            d6 * d6 + d7 * d7;
  }
#pragma unroll
  for (int m = 1; m < 64; m <<= 1) lsum += __shfl_xor(lsum, m, 64);
  if (lane == 0) sSum[wid] = lsum;
  __syncthreads();
  if (t == 0) {
    float s = 0.0f;
#pragma unroll
    for (int w = 0; w < 8; ++w) s += sSum[w];
    partials[bid] = s;
  }
}

__global__ __launch_bounds__(256) void final_reduce(
    const float* __restrict__ partials, float* __restrict__ out) {
  __shared__ float sS[4];
  const int t = threadIdx.x;
  float v = partials[t]; // exactly 256 partials
#pragma unroll
  for (int m = 1; m < 64; m <<= 1) v += __shfl_xor(v, m, 64);
  if ((t & 63) == 0) sS[t >> 6] = v;
  __syncthreads();
  if (t == 0)
    out[0] = (sS[0] + sS[1] + sS[2] + sS[3]) *
             (1.0f / ((float)N_ROWS * (float)D_DIM));
}

extern "C" void kernel_launch(void* const* d_in, const int* in_sizes, int n_in,
                              void* d_out, int out_size, void* d_ws,
                              size_t ws_size, hipStream_t stream) {
  const float* qf = (const float*)d_in[0];  // [32768][512]
  const float* itf = (const float*)d_in[1]; // [4096][512]
  char* ws = (char*)d_ws;
  unsigned char* pk = (unsigned char*)ws;                        // 2 MB fp8
  _Float16* ihl = (_Float16*)(ws + (size_t)M_ITEMS * D_DIM);     // 4 MB fp16
  float* partials =
      (float*)(ws + (size_t)M_ITEMS * D_DIM + (size_t)M_ITEMS * D_DIM * 2);
  float* out = (float*)d_out;

  cast_f32_f16<<<512, 256, 0, stream>>>(itf, ihl, M_ITEMS * D_DIM / 4);
  pack_items_fp8<<<512, 256, 0, stream>>>(itf, pk);
  score_mse<<<N_ROWS / BM, 512, 0, stream>>>(qf, pk, ihl, partials);
  final_reduce<<<1, 256, 0, stream>>>(partials, out);
}